// Round 2
// baseline (20.263 us; speedup 1.0000x reference)
//
#include <hip/hip_runtime.h>
#include <math.h>

// BQNN simulation: 4 lanes per batch element. Each lane redundantly computes
// the 6x3 complex propagated matrix V (10 MZI rotations on the precomputed
// start-matrix columns), then owns 5 of the 20 triple-permanents. Norm is a
// 2-step __shfl_xor reduction within the aligned 4-lane group.

__global__ __launch_bounds__(256) void bqnn_kernel(
    const float* __restrict__ x,            // [B,12]
    const float* __restrict__ params,       // [30]  phi=params[0:15], theta=params[15:30]
    const float* __restrict__ output_phase, // [6]
    const float* __restrict__ param_phi,    // [4]
    const float* __restrict__ param_theta,  // [4]
    const float* __restrict__ input_k,      // [12]
    const float* __restrict__ input_b,      // [12]
    float* __restrict__ out,                // [B,20]
    int B)
{
    __shared__ float sSre[6][3], sSim[6][3];
    __shared__ float sC[4][4];   // {ct, st, epr, epi} for const ansatz MZIs j=0..3
    __shared__ float sK[12], sB[12];

    if (threadIdx.x == 0) {
        // Clements mode list for n=6 (15 MZIs)
        const int CM[15][2] = {{0,1},{2,3},{4,5},{1,2},{3,4},
                               {0,1},{2,3},{4,5},{1,2},{3,4},
                               {0,1},{2,3},{4,5},{1,2},{3,4}};
        float Vre[6][3], Vim[6][3];
        #pragma unroll
        for (int r = 0; r < 6; ++r)
            #pragma unroll
            for (int c = 0; c < 3; ++c) { Vre[r][c] = (r == c) ? 1.f : 0.f; Vim[r][c] = 0.f; }
        for (int k = 0; k < 15; ++k) {
            float ct, st, epr, epi;
            __sincosf(params[15 + k], &st, &ct);
            __sincosf(params[k],      &epi, &epr);
            int m = CM[k][0], n = CM[k][1];
            #pragma unroll
            for (int c = 0; c < 3; ++c) {
                float ar = Vre[m][c], ai = Vim[m][c];
                float br = Vre[n][c], bi = Vim[n][c];
                float tr = epr * ar - epi * ai;
                float ti = epr * ai + epi * ar;
                Vre[m][c] = ct * tr - st * br;
                Vim[m][c] = ct * ti - st * bi;
                Vre[n][c] = st * tr + ct * br;
                Vim[n][c] = st * ti + ct * bi;
            }
        }
        #pragma unroll
        for (int r = 0; r < 6; ++r) {
            float pr, pi;
            __sincosf(output_phase[r], &pi, &pr);
            #pragma unroll
            for (int c = 0; c < 3; ++c) {
                sSre[r][c] = pr * Vre[r][c] - pi * Vim[r][c];
                sSim[r][c] = pr * Vim[r][c] + pi * Vre[r][c];
            }
        }
        #pragma unroll
        for (int j = 0; j < 4; ++j) {
            float ct, st, epr, epi;
            __sincosf(param_theta[j], &st, &ct);
            __sincosf(param_phi[j],   &epi, &epr);
            sC[j][0] = ct; sC[j][1] = st; sC[j][2] = epr; sC[j][3] = epi;
        }
        #pragma unroll
        for (int i = 0; i < 12; ++i) { sK[i] = input_k[i]; sB[i] = input_b[i]; }
    }
    __syncthreads();

    int tid = blockIdx.x * blockDim.x + threadIdx.x;
    int b   = tid >> 2;        // element
    int sub = tid & 3;         // triple-group 0..3 (handles triples 5*sub..5*sub+4)
    if (b >= B) return;

    // xs = x * k + b  (all 4 lanes of the group read the same 48B; L1 broadcast)
    const float4* xp = reinterpret_cast<const float4*>(x + (size_t)b * 12);
    float4 a0 = xp[0], a1 = xp[1], a2 = xp[2];
    float xs[12] = {a0.x, a0.y, a0.z, a0.w, a1.x, a1.y, a1.z, a1.w, a2.x, a2.y, a2.z, a2.w};
    #pragma unroll
    for (int i = 0; i < 12; ++i) xs[i] = xs[i] * sK[i] + sB[i];

    // Ansatz MZI coefficients, k=0..9.
    float ct[10], st[10], epr[10], epi[10];
    __sincosf(xs[3],  &st[0], &ct[0]);  __sincosf(xs[0], &epi[0], &epr[0]);
    __sincosf(xs[4],  &st[1], &ct[1]);  __sincosf(xs[1], &epi[1], &epr[1]);
    __sincosf(xs[5],  &st[2], &ct[2]);  __sincosf(xs[2], &epi[2], &epr[2]);
    ct[3] = sC[0][0]; st[3] = sC[0][1]; epr[3] = sC[0][2]; epi[3] = sC[0][3];
    ct[4] = sC[1][0]; st[4] = sC[1][1]; epr[4] = sC[1][2]; epi[4] = sC[1][3];
    __sincosf(xs[9],  &st[5], &ct[5]);  __sincosf(xs[6], &epi[5], &epr[5]);
    __sincosf(xs[10], &st[6], &ct[6]);  __sincosf(xs[7], &epi[6], &epr[6]);
    __sincosf(xs[11], &st[7], &ct[7]);  __sincosf(xs[8], &epi[7], &epr[7]);
    ct[8] = sC[2][0]; st[8] = sC[2][1]; epr[8] = sC[2][2]; epi[8] = sC[2][3];
    ct[9] = sC[3][0]; st[9] = sC[3][1]; epr[9] = sC[3][2]; epi[9] = sC[3][3];

    // V = S (6x3 complex), then apply 10 left-rotations
    float Vre[6][3], Vim[6][3];
    #pragma unroll
    for (int r = 0; r < 6; ++r)
        #pragma unroll
        for (int c = 0; c < 3; ++c) { Vre[r][c] = sSre[r][c]; Vim[r][c] = sSim[r][c]; }

    const int AM[10][2] = {{0,1},{2,3},{4,5},{1,2},{3,4},{0,1},{2,3},{4,5},{1,2},{3,4}};
    #pragma unroll
    for (int k = 0; k < 10; ++k) {
        int m = AM[k][0], n = AM[k][1];
        #pragma unroll
        for (int c = 0; c < 3; ++c) {
            float ar = Vre[m][c], ai = Vim[m][c];
            float br = Vre[n][c], bi = Vim[n][c];
            float tr = epr[k] * ar - epi[k] * ai;
            float ti = epr[k] * ai + epi[k] * ar;
            Vre[m][c] = ct[k] * tr - st[k] * br;
            Vim[m][c] = ct[k] * ti - st[k] * bi;
            Vre[n][c] = st[k] * tr + ct[k] * br;
            Vim[n][c] = st[k] * ti + ct[k] * bi;
        }
    }

    // This lane's 5 triples: t = 5*sub + i.
    // Triple t = (a, PR[p][0], PR[p][1]); perm expanded along row a using
    // 2x2 pair-permanents q_{c1c2} of the (i,j) row-pair.
    const int TA[20] = {0,0,0,0,0,0,0,0,0,0, 1,1,1,1,1,1, 2,2,2, 3};
    const int TP[20] = {0,1,2,3,4,5,6,7,8,9, 4,5,6,7,8,9, 7,8,9, 9};
    const int PR[10][2] = {{1,2},{1,3},{1,4},{1,5},{2,3},{2,4},{2,5},{3,4},{3,5},{4,5}};

    float sq[5];
    float ssum = 0.f;
    #pragma unroll
    for (int u = 0; u < 5; ++u) {
        int t = 5 * sub + u;
        int a = TA[t];
        int i = PR[TP[t]][0], j = PR[TP[t]][1];

        float q01r = (Vre[i][0]*Vre[j][1] - Vim[i][0]*Vim[j][1]) + (Vre[i][1]*Vre[j][0] - Vim[i][1]*Vim[j][0]);
        float q01i = (Vre[i][0]*Vim[j][1] + Vim[i][0]*Vre[j][1]) + (Vre[i][1]*Vim[j][0] + Vim[i][1]*Vre[j][0]);
        float q02r = (Vre[i][0]*Vre[j][2] - Vim[i][0]*Vim[j][2]) + (Vre[i][2]*Vre[j][0] - Vim[i][2]*Vim[j][0]);
        float q02i = (Vre[i][0]*Vim[j][2] + Vim[i][0]*Vre[j][2]) + (Vre[i][2]*Vim[j][0] + Vim[i][2]*Vre[j][0]);
        float q12r = (Vre[i][1]*Vre[j][2] - Vim[i][1]*Vim[j][2]) + (Vre[i][2]*Vre[j][1] - Vim[i][2]*Vim[j][1]);
        float q12i = (Vre[i][1]*Vim[j][2] + Vim[i][1]*Vre[j][2]) + (Vre[i][2]*Vim[j][1] + Vim[i][2]*Vre[j][1]);

        float pr = (Vre[a][0]*q12r - Vim[a][0]*q12i)
                 + (Vre[a][1]*q02r - Vim[a][1]*q02i)
                 + (Vre[a][2]*q01r - Vim[a][2]*q01i);
        float pi = (Vre[a][0]*q12i + Vim[a][0]*q12r)
                 + (Vre[a][1]*q02i + Vim[a][1]*q02r)
                 + (Vre[a][2]*q01i + Vim[a][2]*q01r);
        sq[u] = pr * pr + pi * pi;
        ssum += sq[u];
    }

    // Norm reduction across the aligned 4-lane group.
    ssum += __shfl_xor(ssum, 1, 64);
    ssum += __shfl_xor(ssum, 2, 64);
    float inv = rsqrtf(fmaxf(ssum, 1e-24f));

    float* op = out + (size_t)b * 20 + sub * 5;
    #pragma unroll
    for (int u = 0; u < 5; ++u) op[u] = sqrtf(sq[u]) * inv;
}

extern "C" void kernel_launch(void* const* d_in, const int* in_sizes, int n_in,
                              void* d_out, int out_size, void* d_ws, size_t ws_size,
                              hipStream_t stream) {
    const float* x            = (const float*)d_in[0];
    const float* params       = (const float*)d_in[1];
    const float* output_phase = (const float*)d_in[2];
    const float* param_phi    = (const float*)d_in[3];
    const float* param_theta  = (const float*)d_in[4];
    const float* input_k      = (const float*)d_in[5];
    const float* input_b      = (const float*)d_in[6];
    int B = in_sizes[0] / 12;

    int block = 256;
    long long threads = (long long)B * 4;
    int grid = (int)((threads + block - 1) / block);
    bqnn_kernel<<<grid, block, 0, stream>>>(x, params, output_phase, param_phi,
                                            param_theta, input_k, input_b,
                                            (float*)d_out, B);
}

// Round 3
// 15.166 us; speedup vs baseline: 1.3361x; 1.3361x over previous
//
#include <hip/hip_runtime.h>
#include <math.h>

// BQNN simulation, two-kernel structure:
//   1) setup_kernel<<<1,1>>>: batch-independent precompute -> d_ws
//      (start-matrix columns 0..2, const-MZI coeffs, input scale/bias)
//   2) bqnn_kernel: 1 thread per batch element, no LDS, no barrier;
//      constants read via wave-uniform (scalar) loads from d_ws.
//
// d_ws float layout:
//   [0..17]   Sre[6][3]
//   [18..35]  Sim[6][3]
//   [36..51]  C[4][4]  = {ct, st, epr, epi} for const ansatz MZIs
//   [52..63]  K[12]
//   [64..75]  Bb[12]

__global__ void setup_kernel(
    const float* __restrict__ params,       // [30] phi=params[0:15], theta=params[15:30]
    const float* __restrict__ output_phase, // [6]
    const float* __restrict__ param_phi,    // [4]
    const float* __restrict__ param_theta,  // [4]
    const float* __restrict__ input_k,      // [12]
    const float* __restrict__ input_b,      // [12]
    float* __restrict__ ws)
{
    // Precompute all sincos up-front (independent -> ILP), then the FMA chain.
    float pct[15], pst[15], per[15], pei[15];
    #pragma unroll
    for (int k = 0; k < 15; ++k) {
        __sincosf(params[15 + k], &pst[k], &pct[k]);
        __sincosf(params[k],      &pei[k], &per[k]);
    }
    const int CM[15][2] = {{0,1},{2,3},{4,5},{1,2},{3,4},
                           {0,1},{2,3},{4,5},{1,2},{3,4},
                           {0,1},{2,3},{4,5},{1,2},{3,4}};
    float Vre[6][3], Vim[6][3];
    #pragma unroll
    for (int r = 0; r < 6; ++r)
        #pragma unroll
        for (int c = 0; c < 3; ++c) { Vre[r][c] = (r == c) ? 1.f : 0.f; Vim[r][c] = 0.f; }
    #pragma unroll
    for (int k = 0; k < 15; ++k) {
        int m = CM[k][0], n = CM[k][1];
        #pragma unroll
        for (int c = 0; c < 3; ++c) {
            float ar = Vre[m][c], ai = Vim[m][c];
            float br = Vre[n][c], bi = Vim[n][c];
            float tr = per[k] * ar - pei[k] * ai;
            float ti = per[k] * ai + pei[k] * ar;
            Vre[m][c] = pct[k] * tr - pst[k] * br;
            Vim[m][c] = pct[k] * ti - pst[k] * bi;
            Vre[n][c] = pst[k] * tr + pct[k] * br;
            Vim[n][c] = pst[k] * ti + pct[k] * bi;
        }
    }
    #pragma unroll
    for (int r = 0; r < 6; ++r) {
        float pr, pi;
        __sincosf(output_phase[r], &pi, &pr);
        #pragma unroll
        for (int c = 0; c < 3; ++c) {
            ws[r * 3 + c]      = pr * Vre[r][c] - pi * Vim[r][c];
            ws[18 + r * 3 + c] = pr * Vim[r][c] + pi * Vre[r][c];
        }
    }
    #pragma unroll
    for (int j = 0; j < 4; ++j) {
        float ct, st, epr, epi;
        __sincosf(param_theta[j], &st, &ct);
        __sincosf(param_phi[j],   &epi, &epr);
        ws[36 + j * 4 + 0] = ct;  ws[36 + j * 4 + 1] = st;
        ws[36 + j * 4 + 2] = epr; ws[36 + j * 4 + 3] = epi;
    }
    #pragma unroll
    for (int i = 0; i < 12; ++i) { ws[52 + i] = input_k[i]; ws[64 + i] = input_b[i]; }
}

__global__ __launch_bounds__(64) void bqnn_kernel(
    const float* __restrict__ x,   // [B,12]
    const float* __restrict__ ws,  // constants (see layout above)
    float* __restrict__ out,       // [B,20]
    int B)
{
    int b = blockIdx.x * blockDim.x + threadIdx.x;
    if (b >= B) return;

    // Wave-uniform constant reads (scalar loads).
    float Sre[6][3], Sim[6][3];
    #pragma unroll
    for (int r = 0; r < 6; ++r)
        #pragma unroll
        for (int c = 0; c < 3; ++c) { Sre[r][c] = ws[r * 3 + c]; Sim[r][c] = ws[18 + r * 3 + c]; }
    float sC[4][4];
    #pragma unroll
    for (int j = 0; j < 4; ++j)
        #pragma unroll
        for (int q = 0; q < 4; ++q) sC[j][q] = ws[36 + j * 4 + q];

    // xs = x * k + b
    const float4* xp = reinterpret_cast<const float4*>(x + (size_t)b * 12);
    float4 a0 = xp[0], a1 = xp[1], a2 = xp[2];
    float xs[12] = {a0.x, a0.y, a0.z, a0.w, a1.x, a1.y, a1.z, a1.w, a2.x, a2.y, a2.z, a2.w};
    #pragma unroll
    for (int i = 0; i < 12; ++i) xs[i] = xs[i] * ws[52 + i] + ws[64 + i];

    // Ansatz MZI coefficients, k=0..9.
    // theta = [xs3,xs4,xs5, pt0,pt1, xs9,xs10,xs11, pt2,pt3]
    // phi   = [xs0,xs1,xs2, pp0,pp1, xs6,xs7, xs8,  pp2,pp3]
    float ct[10], st[10], epr[10], epi[10];
    __sincosf(xs[3],  &st[0], &ct[0]);  __sincosf(xs[0], &epi[0], &epr[0]);
    __sincosf(xs[4],  &st[1], &ct[1]);  __sincosf(xs[1], &epi[1], &epr[1]);
    __sincosf(xs[5],  &st[2], &ct[2]);  __sincosf(xs[2], &epi[2], &epr[2]);
    ct[3] = sC[0][0]; st[3] = sC[0][1]; epr[3] = sC[0][2]; epi[3] = sC[0][3];
    ct[4] = sC[1][0]; st[4] = sC[1][1]; epr[4] = sC[1][2]; epi[4] = sC[1][3];
    __sincosf(xs[9],  &st[5], &ct[5]);  __sincosf(xs[6], &epi[5], &epr[5]);
    __sincosf(xs[10], &st[6], &ct[6]);  __sincosf(xs[7], &epi[6], &epr[6]);
    __sincosf(xs[11], &st[7], &ct[7]);  __sincosf(xs[8], &epi[7], &epr[7]);
    ct[8] = sC[2][0]; st[8] = sC[2][1]; epr[8] = sC[2][2]; epi[8] = sC[2][3];
    ct[9] = sC[3][0]; st[9] = sC[3][1]; epr[9] = sC[3][2]; epi[9] = sC[3][3];

    // V = S, then 10 left-rotations (4 dependent layers; columns give 3-way ILP).
    float Vre[6][3], Vim[6][3];
    #pragma unroll
    for (int r = 0; r < 6; ++r)
        #pragma unroll
        for (int c = 0; c < 3; ++c) { Vre[r][c] = Sre[r][c]; Vim[r][c] = Sim[r][c]; }

    const int AM[10][2] = {{0,1},{2,3},{4,5},{1,2},{3,4},{0,1},{2,3},{4,5},{1,2},{3,4}};
    #pragma unroll
    for (int k = 0; k < 10; ++k) {
        int m = AM[k][0], n = AM[k][1];
        #pragma unroll
        for (int c = 0; c < 3; ++c) {
            float ar = Vre[m][c], ai = Vim[m][c];
            float br = Vre[n][c], bi = Vim[n][c];
            float tr = epr[k] * ar - epi[k] * ai;
            float ti = epr[k] * ai + epi[k] * ar;
            Vre[m][c] = ct[k] * tr - st[k] * br;
            Vim[m][c] = ct[k] * ti - st[k] * bi;
            Vre[n][c] = st[k] * tr + ct[k] * br;
            Vim[n][c] = st[k] * ti + ct[k] * bi;
        }
    }

    // 2x2 pair permanents for the 10 row-pairs within rows {1..5}
    const int PR[10][2] = {{1,2},{1,3},{1,4},{1,5},{2,3},{2,4},{2,5},{3,4},{3,5},{4,5}};
    float q01r[10], q01i[10], q02r[10], q02i[10], q12r[10], q12i[10];
    #pragma unroll
    for (int p = 0; p < 10; ++p) {
        int i = PR[p][0], j = PR[p][1];
        q01r[p] = (Vre[i][0]*Vre[j][1] - Vim[i][0]*Vim[j][1]) + (Vre[i][1]*Vre[j][0] - Vim[i][1]*Vim[j][0]);
        q01i[p] = (Vre[i][0]*Vim[j][1] + Vim[i][0]*Vre[j][1]) + (Vre[i][1]*Vim[j][0] + Vim[i][1]*Vre[j][0]);
        q02r[p] = (Vre[i][0]*Vre[j][2] - Vim[i][0]*Vim[j][2]) + (Vre[i][2]*Vre[j][0] - Vim[i][2]*Vim[j][0]);
        q02i[p] = (Vre[i][0]*Vim[j][2] + Vim[i][0]*Vre[j][2]) + (Vre[i][2]*Vim[j][0] + Vim[i][2]*Vre[j][0]);
        q12r[p] = (Vre[i][1]*Vre[j][2] - Vim[i][1]*Vim[j][2]) + (Vre[i][2]*Vre[j][1] - Vim[i][2]*Vim[j][1]);
        q12i[p] = (Vre[i][1]*Vim[j][2] + Vim[i][1]*Vre[j][2]) + (Vre[i][2]*Vim[j][1] + Vim[i][2]*Vre[j][1]);
    }

    // 20 triples (a < b < c): perm = Ma0*q12(b,c) + Ma1*q02(b,c) + Ma2*q01(b,c)
    const int TA[20] = {0,0,0,0,0,0,0,0,0,0, 1,1,1,1,1,1, 2,2,2, 3};
    const int TP[20] = {0,1,2,3,4,5,6,7,8,9, 4,5,6,7,8,9, 7,8,9, 9};
    float sq[20];
    float ssum = 0.f;
    #pragma unroll
    for (int t = 0; t < 20; ++t) {
        int a = TA[t], p = TP[t];
        float pr = (Vre[a][0]*q12r[p] - Vim[a][0]*q12i[p])
                 + (Vre[a][1]*q02r[p] - Vim[a][1]*q02i[p])
                 + (Vre[a][2]*q01r[p] - Vim[a][2]*q01i[p]);
        float pi = (Vre[a][0]*q12i[p] + Vim[a][0]*q12r[p])
                 + (Vre[a][1]*q02i[p] + Vim[a][1]*q02r[p])
                 + (Vre[a][2]*q01i[p] + Vim[a][2]*q01r[p]);
        sq[t] = pr * pr + pi * pi;
        ssum += sq[t];
    }
    float inv = rsqrtf(fmaxf(ssum, 1e-24f));
    float res[20];
    #pragma unroll
    for (int t = 0; t < 20; ++t) res[t] = sqrtf(sq[t]) * inv;

    float4* op = reinterpret_cast<float4*>(out + (size_t)b * 20);
    op[0] = make_float4(res[0],  res[1],  res[2],  res[3]);
    op[1] = make_float4(res[4],  res[5],  res[6],  res[7]);
    op[2] = make_float4(res[8],  res[9],  res[10], res[11]);
    op[3] = make_float4(res[12], res[13], res[14], res[15]);
    op[4] = make_float4(res[16], res[17], res[18], res[19]);
}

extern "C" void kernel_launch(void* const* d_in, const int* in_sizes, int n_in,
                              void* d_out, int out_size, void* d_ws, size_t ws_size,
                              hipStream_t stream) {
    const float* x            = (const float*)d_in[0];
    const float* params       = (const float*)d_in[1];
    const float* output_phase = (const float*)d_in[2];
    const float* param_phi    = (const float*)d_in[3];
    const float* param_theta  = (const float*)d_in[4];
    const float* input_k      = (const float*)d_in[5];
    const float* input_b      = (const float*)d_in[6];
    int B = in_sizes[0] / 12;
    float* ws = (float*)d_ws;

    setup_kernel<<<1, 1, 0, stream>>>(params, output_phase, param_phi, param_theta,
                                      input_k, input_b, ws);

    int block = 64;
    int grid = (B + block - 1) / block;
    bqnn_kernel<<<grid, block, 0, stream>>>(x, ws, (float*)d_out, B);
}

// Round 4
// 14.286 us; speedup vs baseline: 1.4183x; 1.0616x over previous
//
#include <hip/hip_runtime.h>
#include <math.h>

// BQNN simulation, single kernel, 2 batch elements per thread (e, e+B/2).
// Rationale: at 1 elem/thread the grid is 512 waves on 1024 SIMDs -> every
// wave runs alone, fully latency-exposed. Two independent element chains per
// thread give 2-way ILP at zero redundant work. The batch-independent
// preamble's 44 sincos are computed one-per-lane and shared via LDS.

__global__ __launch_bounds__(64) void bqnn_kernel(
    const float* __restrict__ x,            // [B,12]
    const float* __restrict__ params,       // [30] phi=params[0:15], theta=params[15:30]
    const float* __restrict__ output_phase, // [6]
    const float* __restrict__ param_phi,    // [4]
    const float* __restrict__ param_theta,  // [4]
    const float* __restrict__ input_k,      // [12]
    const float* __restrict__ input_b,      // [12]
    float* __restrict__ out,                // [B,20]
    int B)
{
    // ---- Preamble part 1: 44 sincos, one per lane, shared via LDS ----
    // lane i: i<15 -> theta_i=params[15+i]; i<30 -> phi=params[i-15];
    // i<36 -> output_phase[i-30]; i<40 -> param_theta[i-36]; i<44 -> param_phi[i-40]
    __shared__ float sc[88];   // sc[2i]=sin(arg_i), sc[2i+1]=cos(arg_i)
    int lane = threadIdx.x;
    if (lane < 44) {
        float arg;
        if      (lane < 15) arg = params[15 + lane];
        else if (lane < 30) arg = params[lane - 15];
        else if (lane < 36) arg = output_phase[lane - 30];
        else if (lane < 40) arg = param_theta[lane - 36];
        else                arg = param_phi[lane - 40];
        float s, c;
        __sincosf(arg, &s, &c);
        sc[2 * lane]     = s;
        sc[2 * lane + 1] = c;
    }
    __syncthreads();

    // ---- Preamble part 2: 15-MZI Clements chain (all lanes redundantly;
    //      uniform LDS reads broadcast, wave time same as masked) ----
    const int CM[15][2] = {{0,1},{2,3},{4,5},{1,2},{3,4},
                           {0,1},{2,3},{4,5},{1,2},{3,4},
                           {0,1},{2,3},{4,5},{1,2},{3,4}};
    float Sre[6][3], Sim[6][3];
    #pragma unroll
    for (int r = 0; r < 6; ++r)
        #pragma unroll
        for (int c = 0; c < 3; ++c) { Sre[r][c] = (r == c) ? 1.f : 0.f; Sim[r][c] = 0.f; }
    #pragma unroll
    for (int k = 0; k < 15; ++k) {
        float pst = sc[2 * k],        pct = sc[2 * k + 1];
        float pei = sc[2 * (15 + k)], per = sc[2 * (15 + k) + 1];
        int m = CM[k][0], n = CM[k][1];
        #pragma unroll
        for (int c = 0; c < 3; ++c) {
            float ar = Sre[m][c], ai = Sim[m][c];
            float br = Sre[n][c], bi = Sim[n][c];
            float tr = per * ar - pei * ai;
            float ti = per * ai + pei * ar;
            Sre[m][c] = pct * tr - pst * br;
            Sim[m][c] = pct * ti - pst * bi;
            Sre[n][c] = pst * tr + pct * br;
            Sim[n][c] = pst * ti + pct * bi;
        }
    }
    #pragma unroll
    for (int r = 0; r < 6; ++r) {
        float pi = sc[2 * (30 + r)], pr = sc[2 * (30 + r) + 1];
        #pragma unroll
        for (int c = 0; c < 3; ++c) {
            float vr = Sre[r][c], vi = Sim[r][c];
            Sre[r][c] = pr * vr - pi * vi;
            Sim[r][c] = pr * vi + pi * vr;
        }
    }

    // ---- Per-thread: two elements e0 = tid, e1 = tid + half ----
    int half = (B + 1) >> 1;
    int tid = blockIdx.x * blockDim.x + threadIdx.x;
    if (tid >= half) return;
    int e1v = tid + half;
    bool has1 = (e1v < B);
    int eidx[2] = { tid, has1 ? e1v : tid };   // duplicate harmlessly if odd B

    // Loads + xs affine
    float xs[2][12];
    #pragma unroll
    for (int e = 0; e < 2; ++e) {
        const float4* xp = reinterpret_cast<const float4*>(x + (size_t)eidx[e] * 12);
        float4 a0 = xp[0], a1 = xp[1], a2 = xp[2];
        float t[12] = {a0.x, a0.y, a0.z, a0.w, a1.x, a1.y, a1.z, a1.w, a2.x, a2.y, a2.z, a2.w};
        #pragma unroll
        for (int i = 0; i < 12; ++i) xs[e][i] = t[i] * input_k[i] + input_b[i];
    }

    // Ansatz MZI coefficients (data-dependent: 12 sincos per element, interleaved)
    // theta = [xs3,xs4,xs5, pt0,pt1, xs9,xs10,xs11, pt2,pt3]
    // phi   = [xs0,xs1,xs2, pp0,pp1, xs6,xs7, xs8,  pp2,pp3]
    float ct[2][10], st[2][10], epr[2][10], epi[2][10];
    #pragma unroll
    for (int e = 0; e < 2; ++e) {
        __sincosf(xs[e][3],  &st[e][0], &ct[e][0]);  __sincosf(xs[e][0], &epi[e][0], &epr[e][0]);
        __sincosf(xs[e][4],  &st[e][1], &ct[e][1]);  __sincosf(xs[e][1], &epi[e][1], &epr[e][1]);
        __sincosf(xs[e][5],  &st[e][2], &ct[e][2]);  __sincosf(xs[e][2], &epi[e][2], &epr[e][2]);
        st[e][3] = sc[2*36]; ct[e][3] = sc[2*36+1];  epi[e][3] = sc[2*40]; epr[e][3] = sc[2*40+1];
        st[e][4] = sc[2*37]; ct[e][4] = sc[2*37+1];  epi[e][4] = sc[2*41]; epr[e][4] = sc[2*41+1];
        __sincosf(xs[e][9],  &st[e][5], &ct[e][5]);  __sincosf(xs[e][6], &epi[e][5], &epr[e][5]);
        __sincosf(xs[e][10], &st[e][6], &ct[e][6]);  __sincosf(xs[e][7], &epi[e][6], &epr[e][6]);
        __sincosf(xs[e][11], &st[e][7], &ct[e][7]);  __sincosf(xs[e][8], &epi[e][7], &epr[e][7]);
        st[e][8] = sc[2*38]; ct[e][8] = sc[2*38+1];  epi[e][8] = sc[2*42]; epr[e][8] = sc[2*42+1];
        st[e][9] = sc[2*39]; ct[e][9] = sc[2*39+1];  epi[e][9] = sc[2*43]; epr[e][9] = sc[2*43+1];
    }

    // V = S, then 10 left-rotations; both elements interleaved for ILP
    float Vre[2][6][3], Vim[2][6][3];
    #pragma unroll
    for (int e = 0; e < 2; ++e)
        #pragma unroll
        for (int r = 0; r < 6; ++r)
            #pragma unroll
            for (int c = 0; c < 3; ++c) { Vre[e][r][c] = Sre[r][c]; Vim[e][r][c] = Sim[r][c]; }

    const int AM[10][2] = {{0,1},{2,3},{4,5},{1,2},{3,4},{0,1},{2,3},{4,5},{1,2},{3,4}};
    #pragma unroll
    for (int k = 0; k < 10; ++k) {
        int m = AM[k][0], n = AM[k][1];
        #pragma unroll
        for (int e = 0; e < 2; ++e) {
            #pragma unroll
            for (int c = 0; c < 3; ++c) {
                float ar = Vre[e][m][c], ai = Vim[e][m][c];
                float br = Vre[e][n][c], bi = Vim[e][n][c];
                float tr = epr[e][k] * ar - epi[e][k] * ai;
                float ti = epr[e][k] * ai + epi[e][k] * ar;
                Vre[e][m][c] = ct[e][k] * tr - st[e][k] * br;
                Vim[e][m][c] = ct[e][k] * ti - st[e][k] * bi;
                Vre[e][n][c] = st[e][k] * tr + ct[e][k] * br;
                Vim[e][n][c] = st[e][k] * ti + ct[e][k] * bi;
            }
        }
    }

    // Permanents: per row-pair p compute the three 2x2 pair-permanents and
    // immediately consume them into the triples that reference p (transient q).
    const int PR[10][2] = {{1,2},{1,3},{1,4},{1,5},{2,3},{2,4},{2,5},{3,4},{3,5},{4,5}};
    // triples grouped by pair index p: TA lists the "a" rows whose triple uses p
    // t(a,p): p=0..9 with a=0; additionally a=1 for p>=4, a=2 for p>=7, a=3 for p==9.
    // Output index of triple (a,p): precomputed table.
    // a=0: t=p (0..9); a=1,p=4..9: t=10+(p-4); a=2,p=7..9: t=16+(p-7); a=3,p=9: t=19.
    float sq[2][20];
    float ssum[2] = {0.f, 0.f};
    #pragma unroll
    for (int p = 0; p < 10; ++p) {
        int i = PR[p][0], j = PR[p][1];
        #pragma unroll
        for (int e = 0; e < 2; ++e) {
            float q01r = (Vre[e][i][0]*Vre[e][j][1] - Vim[e][i][0]*Vim[e][j][1]) + (Vre[e][i][1]*Vre[e][j][0] - Vim[e][i][1]*Vim[e][j][0]);
            float q01i = (Vre[e][i][0]*Vim[e][j][1] + Vim[e][i][0]*Vre[e][j][1]) + (Vre[e][i][1]*Vim[e][j][0] + Vim[e][i][1]*Vre[e][j][0]);
            float q02r = (Vre[e][i][0]*Vre[e][j][2] - Vim[e][i][0]*Vim[e][j][2]) + (Vre[e][i][2]*Vre[e][j][0] - Vim[e][i][2]*Vim[e][j][0]);
            float q02i = (Vre[e][i][0]*Vim[e][j][2] + Vim[e][i][0]*Vre[e][j][2]) + (Vre[e][i][2]*Vim[e][j][0] + Vim[e][i][2]*Vre[e][j][0]);
            float q12r = (Vre[e][i][1]*Vre[e][j][2] - Vim[e][i][1]*Vim[e][j][2]) + (Vre[e][i][2]*Vre[e][j][1] - Vim[e][i][2]*Vim[e][j][1]);
            float q12i = (Vre[e][i][1]*Vim[e][j][2] + Vim[e][i][1]*Vre[e][j][2]) + (Vre[e][i][2]*Vim[e][j][1] + Vim[e][i][2]*Vre[e][j][1]);
            #pragma unroll
            for (int a = 0; a < 4; ++a) {
                // does triple (a, p) exist?
                if ((a == 0) || (a == 1 && p >= 4) || (a == 2 && p >= 7) || (a == 3 && p == 9)) {
                    int t = (a == 0) ? p : (a == 1) ? 10 + (p - 4) : (a == 2) ? 16 + (p - 7) : 19;
                    float pr = (Vre[e][a][0]*q12r - Vim[e][a][0]*q12i)
                             + (Vre[e][a][1]*q02r - Vim[e][a][1]*q02i)
                             + (Vre[e][a][2]*q01r - Vim[e][a][2]*q01i);
                    float pi = (Vre[e][a][0]*q12i + Vim[e][a][0]*q12r)
                             + (Vre[e][a][1]*q02i + Vim[e][a][1]*q02r)
                             + (Vre[e][a][2]*q01i + Vim[e][a][2]*q01r);
                    sq[e][t] = pr * pr + pi * pi;
                    ssum[e] += sq[e][t];
                }
            }
        }
    }

    #pragma unroll
    for (int e = 0; e < 2; ++e) {
        if (e == 1 && !has1) break;
        float inv = rsqrtf(fmaxf(ssum[e], 1e-24f));
        float res[20];
        #pragma unroll
        for (int t = 0; t < 20; ++t) res[t] = sqrtf(sq[e][t]) * inv;
        float4* op = reinterpret_cast<float4*>(out + (size_t)eidx[e] * 20);
        op[0] = make_float4(res[0],  res[1],  res[2],  res[3]);
        op[1] = make_float4(res[4],  res[5],  res[6],  res[7]);
        op[2] = make_float4(res[8],  res[9],  res[10], res[11]);
        op[3] = make_float4(res[12], res[13], res[14], res[15]);
        op[4] = make_float4(res[16], res[17], res[18], res[19]);
    }
}

extern "C" void kernel_launch(void* const* d_in, const int* in_sizes, int n_in,
                              void* d_out, int out_size, void* d_ws, size_t ws_size,
                              hipStream_t stream) {
    const float* x            = (const float*)d_in[0];
    const float* params       = (const float*)d_in[1];
    const float* output_phase = (const float*)d_in[2];
    const float* param_phi    = (const float*)d_in[3];
    const float* param_theta  = (const float*)d_in[4];
    const float* input_k      = (const float*)d_in[5];
    const float* input_b      = (const float*)d_in[6];
    int B = in_sizes[0] / 12;

    int half = (B + 1) / 2;
    int block = 64;
    int grid = (half + block - 1) / block;
    bqnn_kernel<<<grid, block, 0, stream>>>(x, params, output_phase, param_phi,
                                            param_theta, input_k, input_b,
                                            (float*)d_out, B);
}

// Round 5
// 11.995 us; speedup vs baseline: 1.6893x; 1.1910x over previous
//
#include <hip/hip_runtime.h>
#include <math.h>

// BQNN simulation, single kernel, 1 batch element per thread (R1 structure,
// lowest-VGPR variant, E~3us) with two latency fixes:
//  - per-element x loads issued BEFORE the preamble (HBM latency hidden)
//  - the 44 batch-independent sincos computed one-per-lane -> LDS (one trans
//    step instead of 44 serially under a 1-lane exec mask); the 15-MZI
//    Clements chain then runs wave-wide on broadcast LDS reads.

__global__ __launch_bounds__(64) void bqnn_kernel(
    const float* __restrict__ x,            // [B,12]
    const float* __restrict__ params,       // [30] phi=params[0:15], theta=params[15:30]
    const float* __restrict__ output_phase, // [6]
    const float* __restrict__ param_phi,    // [4]
    const float* __restrict__ param_theta,  // [4]
    const float* __restrict__ input_k,      // [12]
    const float* __restrict__ input_b,      // [12]
    float* __restrict__ out,                // [B,20]
    int B)
{
    __shared__ float sc[88];   // sc[2i]=sin(arg_i), sc[2i+1]=cos(arg_i)
    int lane = threadIdx.x;
    int b = blockIdx.x * 64 + lane;
    int bl = (b < B) ? b : (B - 1);

    // ---- Issue per-element loads early; latency hides under the preamble ----
    const float4* xp = reinterpret_cast<const float4*>(x + (size_t)bl * 12);
    float4 a0 = xp[0], a1 = xp[1], a2 = xp[2];

    // ---- Preamble part 1: 44 sincos, one per lane, shared via LDS ----
    // lane i: i<15 -> theta_i=params[15+i]; i<30 -> phi_{i-15}=params[i-15];
    // i<36 -> output_phase[i-30]; i<40 -> param_theta[i-36]; i<44 -> param_phi[i-40]
    if (lane < 44) {
        float arg;
        if      (lane < 15) arg = params[15 + lane];
        else if (lane < 30) arg = params[lane - 15];
        else if (lane < 36) arg = output_phase[lane - 30];
        else if (lane < 40) arg = param_theta[lane - 36];
        else                arg = param_phi[lane - 40];
        float s, c;
        __sincosf(arg, &s, &c);
        sc[2 * lane]     = s;
        sc[2 * lane + 1] = c;
    }
    __syncthreads();

    // ---- Preamble part 2: 15-MZI Clements chain, wave-wide (broadcast LDS) ----
    const int CM[15][2] = {{0,1},{2,3},{4,5},{1,2},{3,4},
                           {0,1},{2,3},{4,5},{1,2},{3,4},
                           {0,1},{2,3},{4,5},{1,2},{3,4}};
    float Vre[6][3], Vim[6][3];
    #pragma unroll
    for (int r = 0; r < 6; ++r)
        #pragma unroll
        for (int c = 0; c < 3; ++c) { Vre[r][c] = (r == c) ? 1.f : 0.f; Vim[r][c] = 0.f; }
    #pragma unroll
    for (int k = 0; k < 15; ++k) {
        float pst = sc[2 * k],        pct = sc[2 * k + 1];
        float pei = sc[2 * (15 + k)], per = sc[2 * (15 + k) + 1];
        int m = CM[k][0], n = CM[k][1];
        #pragma unroll
        for (int c = 0; c < 3; ++c) {
            float ar = Vre[m][c], ai = Vim[m][c];
            float br = Vre[n][c], bi = Vim[n][c];
            float tr = per * ar - pei * ai;
            float ti = per * ai + pei * ar;
            Vre[m][c] = pct * tr - pst * br;
            Vim[m][c] = pct * ti - pst * bi;
            Vre[n][c] = pst * tr + pct * br;
            Vim[n][c] = pst * ti + pct * bi;
        }
    }
    #pragma unroll
    for (int r = 0; r < 6; ++r) {
        float pi = sc[2 * (30 + r)], pr = sc[2 * (30 + r) + 1];
        #pragma unroll
        for (int c = 0; c < 3; ++c) {
            float vr = Vre[r][c], vi = Vim[r][c];
            Vre[r][c] = pr * vr - pi * vi;
            Vim[r][c] = pr * vi + pi * vr;
        }
    }

    // ---- Per-element work ----
    float xs[12] = {a0.x, a0.y, a0.z, a0.w, a1.x, a1.y, a1.z, a1.w, a2.x, a2.y, a2.z, a2.w};
    #pragma unroll
    for (int i = 0; i < 12; ++i) xs[i] = xs[i] * input_k[i] + input_b[i];

    // Ansatz MZI coefficients, k=0..9.
    // theta = [xs3,xs4,xs5, pt0,pt1, xs9,xs10,xs11, pt2,pt3]
    // phi   = [xs0,xs1,xs2, pp0,pp1, xs6,xs7, xs8,  pp2,pp3]
    float ct[10], st[10], epr[10], epi[10];
    __sincosf(xs[3],  &st[0], &ct[0]);  __sincosf(xs[0], &epi[0], &epr[0]);
    __sincosf(xs[4],  &st[1], &ct[1]);  __sincosf(xs[1], &epi[1], &epr[1]);
    __sincosf(xs[5],  &st[2], &ct[2]);  __sincosf(xs[2], &epi[2], &epr[2]);
    st[3] = sc[2*36]; ct[3] = sc[2*36+1];  epi[3] = sc[2*40]; epr[3] = sc[2*40+1];
    st[4] = sc[2*37]; ct[4] = sc[2*37+1];  epi[4] = sc[2*41]; epr[4] = sc[2*41+1];
    __sincosf(xs[9],  &st[5], &ct[5]);  __sincosf(xs[6], &epi[5], &epr[5]);
    __sincosf(xs[10], &st[6], &ct[6]);  __sincosf(xs[7], &epi[6], &epr[6]);
    __sincosf(xs[11], &st[7], &ct[7]);  __sincosf(xs[8], &epi[7], &epr[7]);
    st[8] = sc[2*38]; ct[8] = sc[2*38+1];  epi[8] = sc[2*42]; epr[8] = sc[2*42+1];
    st[9] = sc[2*39]; ct[9] = sc[2*39+1];  epi[9] = sc[2*43]; epr[9] = sc[2*43+1];

    // Apply 10 left-rotations to V (= S)
    const int AM[10][2] = {{0,1},{2,3},{4,5},{1,2},{3,4},{0,1},{2,3},{4,5},{1,2},{3,4}};
    #pragma unroll
    for (int k = 0; k < 10; ++k) {
        int m = AM[k][0], n = AM[k][1];
        #pragma unroll
        for (int c = 0; c < 3; ++c) {
            float ar = Vre[m][c], ai = Vim[m][c];
            float br = Vre[n][c], bi = Vim[n][c];
            float tr = epr[k] * ar - epi[k] * ai;
            float ti = epr[k] * ai + epi[k] * ar;
            Vre[m][c] = ct[k] * tr - st[k] * br;
            Vim[m][c] = ct[k] * ti - st[k] * bi;
            Vre[n][c] = st[k] * tr + ct[k] * br;
            Vim[n][c] = st[k] * ti + ct[k] * bi;
        }
    }

    // 2x2 pair permanents for the 10 row-pairs within rows {1..5}
    const int PR[10][2] = {{1,2},{1,3},{1,4},{1,5},{2,3},{2,4},{2,5},{3,4},{3,5},{4,5}};
    float q01r[10], q01i[10], q02r[10], q02i[10], q12r[10], q12i[10];
    #pragma unroll
    for (int p = 0; p < 10; ++p) {
        int i = PR[p][0], j = PR[p][1];
        q01r[p] = (Vre[i][0]*Vre[j][1] - Vim[i][0]*Vim[j][1]) + (Vre[i][1]*Vre[j][0] - Vim[i][1]*Vim[j][0]);
        q01i[p] = (Vre[i][0]*Vim[j][1] + Vim[i][0]*Vre[j][1]) + (Vre[i][1]*Vim[j][0] + Vim[i][1]*Vre[j][0]);
        q02r[p] = (Vre[i][0]*Vre[j][2] - Vim[i][0]*Vim[j][2]) + (Vre[i][2]*Vre[j][0] - Vim[i][2]*Vim[j][0]);
        q02i[p] = (Vre[i][0]*Vim[j][2] + Vim[i][0]*Vre[j][2]) + (Vre[i][2]*Vim[j][0] + Vim[i][2]*Vre[j][0]);
        q12r[p] = (Vre[i][1]*Vre[j][2] - Vim[i][1]*Vim[j][2]) + (Vre[i][2]*Vre[j][1] - Vim[i][2]*Vim[j][1]);
        q12i[p] = (Vre[i][1]*Vim[j][2] + Vim[i][1]*Vre[j][2]) + (Vre[i][2]*Vim[j][1] + Vim[i][2]*Vre[j][1]);
    }

    // 20 triples (a < b < c): perm = Ma0*q12(b,c) + Ma1*q02(b,c) + Ma2*q01(b,c)
    const int TA[20] = {0,0,0,0,0,0,0,0,0,0, 1,1,1,1,1,1, 2,2,2, 3};
    const int TP[20] = {0,1,2,3,4,5,6,7,8,9, 4,5,6,7,8,9, 7,8,9, 9};
    float sq[20];
    float ssum = 0.f;
    #pragma unroll
    for (int t = 0; t < 20; ++t) {
        int a = TA[t], p = TP[t];
        float pr = (Vre[a][0]*q12r[p] - Vim[a][0]*q12i[p])
                 + (Vre[a][1]*q02r[p] - Vim[a][1]*q02i[p])
                 + (Vre[a][2]*q01r[p] - Vim[a][2]*q01i[p]);
        float pi = (Vre[a][0]*q12i[p] + Vim[a][0]*q12r[p])
                 + (Vre[a][1]*q02i[p] + Vim[a][1]*q02r[p])
                 + (Vre[a][2]*q01i[p] + Vim[a][2]*q01r[p]);
        sq[t] = pr * pr + pi * pi;
        ssum += sq[t];
    }
    float inv = rsqrtf(fmaxf(ssum, 1e-24f));

    if (b < B) {
        float res[20];
        #pragma unroll
        for (int t = 0; t < 20; ++t) res[t] = sqrtf(sq[t]) * inv;
        float4* op = reinterpret_cast<float4*>(out + (size_t)b * 20);
        op[0] = make_float4(res[0],  res[1],  res[2],  res[3]);
        op[1] = make_float4(res[4],  res[5],  res[6],  res[7]);
        op[2] = make_float4(res[8],  res[9],  res[10], res[11]);
        op[3] = make_float4(res[12], res[13], res[14], res[15]);
        op[4] = make_float4(res[16], res[17], res[18], res[19]);
    }
}

extern "C" void kernel_launch(void* const* d_in, const int* in_sizes, int n_in,
                              void* d_out, int out_size, void* d_ws, size_t ws_size,
                              hipStream_t stream) {
    const float* x            = (const float*)d_in[0];
    const float* params       = (const float*)d_in[1];
    const float* output_phase = (const float*)d_in[2];
    const float* param_phi    = (const float*)d_in[3];
    const float* param_theta  = (const float*)d_in[4];
    const float* input_k      = (const float*)d_in[5];
    const float* input_b      = (const float*)d_in[6];
    int B = in_sizes[0] / 12;

    int block = 64;
    int grid = (B + block - 1) / block;
    bqnn_kernel<<<grid, block, 0, stream>>>(x, params, output_phase, param_phi,
                                            param_theta, input_k, input_b,
                                            (float*)d_out, B);
}

// Round 6
// 10.889 us; speedup vs baseline: 1.8609x; 1.1016x over previous
//
#include <hip/hip_runtime.h>
#include <math.h>

// BQNN simulation. 2 lanes per batch element, 1024 waves (all SIMDs covered).
//  - 44 batch-independent sincos: one per lane -> LDS (R5, verified)
//  - 15-MZI Clements chain: LANE-PARALLEL (lane l<18 holds entry (r=l/3,c=l%3);
//    disjoint MZIs fused -> 6 shuffle steps), shared back via LDS
//  - per-element: x loads issued early; 10-MZI ansatz rotation (per-lane, as R5)
//  - permanents: lanes sub=0/1 run IDENTICAL static code on row-view
//    U = sub ? V[5-r] : V[r]; the 10 canonical triples on reversed rows are
//    exactly the complementary 10 of the 20 outputs (row-reversal orbit split),
//    so the pair covers all 20 with zero redundancy and no divergent math.

__global__ __launch_bounds__(64) void bqnn_kernel(
    const float* __restrict__ x,            // [B,12]
    const float* __restrict__ params,       // [30] phi=params[0:15], theta=params[15:30]
    const float* __restrict__ output_phase, // [6]
    const float* __restrict__ param_phi,    // [4]
    const float* __restrict__ param_theta,  // [4]
    const float* __restrict__ input_k,      // [12]
    const float* __restrict__ input_b,      // [12]
    float* __restrict__ out,                // [B,20]
    int B)
{
    __shared__ float sc[88];   // sc[2i]=sin(arg_i), sc[2i+1]=cos(arg_i)
    __shared__ float sS[36];   // final start-matrix: re at 2*(r*3+c), im at +1

    int l = threadIdx.x;
    long long tid = (long long)blockIdx.x * 64 + l;
    int e   = (int)(tid >> 1);
    int sub = (int)(tid & 1);
    int el  = (e < B) ? e : (B - 1);

    // ---- Issue per-element loads early; latency hides under the preamble ----
    const float4* xp = reinterpret_cast<const float4*>(x + (size_t)el * 12);
    float4 a0 = xp[0], a1 = xp[1], a2 = xp[2];

    // ---- Preamble 1: 44 sincos, one per lane -> LDS ----
    if (l < 44) {
        float arg;
        if      (l < 15) arg = params[15 + l];
        else if (l < 30) arg = params[l - 15];
        else if (l < 36) arg = output_phase[l - 30];
        else if (l < 40) arg = param_theta[l - 36];
        else             arg = param_phi[l - 40];
        float s, c;
        __sincosf(arg, &s, &c);
        sc[2 * l]     = s;
        sc[2 * l + 1] = c;
    }
    __syncthreads();

    // ---- Preamble 2: lane-parallel Clements chain ----
    // lane l<18 holds U[r][c], r=l/3, c=l%3; others compute junk (never shared).
    int ls = (l < 18) ? l : 0;
    int r_ = ls / 3, c_ = ls - 3 * r_;
    bool upperA = ((r_ & 1) == 0);
    int  pA = (r_ ^ 1) * 3 + c_;                               // type-A partner lane
    int  mB = (r_ == 1) ? 2 : (r_ == 2) ? 1 : (r_ == 3) ? 4 : (r_ == 4) ? 3 : r_;
    int  pB = mB * 3 + c_;                                     // type-B partner lane
    bool activeB = (r_ >= 1 && r_ <= 4);
    bool upperB  = (r_ == 1) || (r_ == 3);
    int  kA = r_ >> 1;                                         // A-step MZI sub-index
    int  kB = (r_ >= 3) ? 1 : 0;                               // B-step MZI sub-index

    float ur = (r_ == c_) ? 1.f : 0.f;
    float ui = 0.f;

    #pragma unroll
    for (int g = 0; g < 3; ++g) {
        {   // A step: MZIs 5g+{0,1,2} on row pairs (0,1),(2,3),(4,5)
            int kk = 5 * g + kA;
            float pst = sc[2 * kk],        pct = sc[2 * kk + 1];
            float pei = sc[2 * (15 + kk)], per = sc[2 * (15 + kk) + 1];
            float wr = __shfl(ur, pA, 64), wi = __shfl(ui, pA, 64);
            float srr = upperA ? ur : wr,  sii = upperA ? ui : wi;
            float orr = upperA ? wr : ur,  oii = upperA ? wi : ui;
            float tr = per * srr - pei * sii;
            float ti = per * sii + pei * srr;
            float cA = upperA ? pct : pst;
            float cB = upperA ? -pst : pct;
            ur = cA * tr + cB * orr;
            ui = cA * ti + cB * oii;
        }
        {   // B step: MZIs 5g+3+{0,1} on row pairs (1,2),(3,4); rows 0,5 pass
            int kk = 5 * g + 3 + kB;
            float pst = sc[2 * kk],        pct = sc[2 * kk + 1];
            float pei = sc[2 * (15 + kk)], per = sc[2 * (15 + kk) + 1];
            float wr = __shfl(ur, pB, 64), wi = __shfl(ui, pB, 64);
            float srr = upperB ? ur : wr,  sii = upperB ? ui : wi;
            float orr = upperB ? wr : ur,  oii = upperB ? wi : ui;
            float tr = per * srr - pei * sii;
            float ti = per * sii + pei * srr;
            float cA = upperB ? pct : pst;
            float cB = upperB ? -pst : pct;
            float nr = cA * tr + cB * orr;
            float ni = cA * ti + cB * oii;
            ur = activeB ? nr : ur;
            ui = activeB ? ni : ui;
        }
    }
    // output phase on row r_
    {
        float opi = sc[2 * (30 + r_)], opr_ = sc[2 * (30 + r_) + 1];
        float nr = opr_ * ur - opi * ui;
        float ni = opr_ * ui + opi * ur;
        ur = nr; ui = ni;
    }
    if (l < 18) { sS[2 * l] = ur; sS[2 * l + 1] = ui; }
    __syncthreads();

    float Sre[6][3], Sim[6][3];
    #pragma unroll
    for (int r = 0; r < 6; ++r)
        #pragma unroll
        for (int c = 0; c < 3; ++c) {
            Sre[r][c] = sS[2 * (r * 3 + c)];
            Sim[r][c] = sS[2 * (r * 3 + c) + 1];
        }

    // ---- Per-element work (both lanes of the pair do rotation redundantly) ----
    float xs[12] = {a0.x, a0.y, a0.z, a0.w, a1.x, a1.y, a1.z, a1.w, a2.x, a2.y, a2.z, a2.w};
    #pragma unroll
    for (int i = 0; i < 12; ++i) xs[i] = xs[i] * input_k[i] + input_b[i];

    float ct[10], st[10], epr[10], epi[10];
    __sincosf(xs[3],  &st[0], &ct[0]);  __sincosf(xs[0], &epi[0], &epr[0]);
    __sincosf(xs[4],  &st[1], &ct[1]);  __sincosf(xs[1], &epi[1], &epr[1]);
    __sincosf(xs[5],  &st[2], &ct[2]);  __sincosf(xs[2], &epi[2], &epr[2]);
    st[3] = sc[2*36]; ct[3] = sc[2*36+1];  epi[3] = sc[2*40]; epr[3] = sc[2*40+1];
    st[4] = sc[2*37]; ct[4] = sc[2*37+1];  epi[4] = sc[2*41]; epr[4] = sc[2*41+1];
    __sincosf(xs[9],  &st[5], &ct[5]);  __sincosf(xs[6], &epi[5], &epr[5]);
    __sincosf(xs[10], &st[6], &ct[6]);  __sincosf(xs[7], &epi[6], &epr[6]);
    __sincosf(xs[11], &st[7], &ct[7]);  __sincosf(xs[8], &epi[7], &epr[7]);
    st[8] = sc[2*38]; ct[8] = sc[2*38+1];  epi[8] = sc[2*42]; epr[8] = sc[2*42+1];
    st[9] = sc[2*39]; ct[9] = sc[2*39+1];  epi[9] = sc[2*43]; epr[9] = sc[2*43+1];

    float Vre[6][3], Vim[6][3];
    #pragma unroll
    for (int r = 0; r < 6; ++r)
        #pragma unroll
        for (int c = 0; c < 3; ++c) { Vre[r][c] = Sre[r][c]; Vim[r][c] = Sim[r][c]; }

    const int AM[10][2] = {{0,1},{2,3},{4,5},{1,2},{3,4},{0,1},{2,3},{4,5},{1,2},{3,4}};
    #pragma unroll
    for (int k = 0; k < 10; ++k) {
        int m = AM[k][0], n = AM[k][1];
        #pragma unroll
        for (int c = 0; c < 3; ++c) {
            float ar = Vre[m][c], ai = Vim[m][c];
            float br = Vre[n][c], bi = Vim[n][c];
            float tr = epr[k] * ar - epi[k] * ai;
            float ti = epr[k] * ai + epi[k] * ar;
            Vre[m][c] = ct[k] * tr - st[k] * br;
            Vim[m][c] = ct[k] * ti - st[k] * bi;
            Vre[n][c] = st[k] * tr + ct[k] * br;
            Vim[n][c] = st[k] * ti + ct[k] * bi;
        }
    }

    // ---- Row-view select: U = sub ? reversed-rows V : V (static indices) ----
    float Ure[6][3], Uim[6][3];
    #pragma unroll
    for (int r = 0; r < 6; ++r)
        #pragma unroll
        for (int c = 0; c < 3; ++c) {
            Ure[r][c] = sub ? Vre[5 - r][c] : Vre[r][c];
            Uim[r][c] = sub ? Vim[5 - r][c] : Vim[r][c];
        }

    // ---- 8 pair-permanents on U row-pairs ----
    const int PR2[8][2] = {{1,2},{1,3},{1,4},{1,5},{2,3},{2,4},{2,5},{3,4}};
    float q01r[8], q01i[8], q02r[8], q02i[8], q12r[8], q12i[8];
    #pragma unroll
    for (int p = 0; p < 8; ++p) {
        int i = PR2[p][0], j = PR2[p][1];
        q01r[p] = (Ure[i][0]*Ure[j][1] - Uim[i][0]*Uim[j][1]) + (Ure[i][1]*Ure[j][0] - Uim[i][1]*Uim[j][0]);
        q01i[p] = (Ure[i][0]*Uim[j][1] + Uim[i][0]*Ure[j][1]) + (Ure[i][1]*Uim[j][0] + Uim[i][1]*Ure[j][0]);
        q02r[p] = (Ure[i][0]*Ure[j][2] - Uim[i][0]*Uim[j][2]) + (Ure[i][2]*Ure[j][0] - Uim[i][2]*Uim[j][0]);
        q02i[p] = (Ure[i][0]*Uim[j][2] + Uim[i][0]*Ure[j][2]) + (Ure[i][2]*Uim[j][0] + Uim[i][2]*Ure[j][0]);
        q12r[p] = (Ure[i][1]*Ure[j][2] - Uim[i][1]*Uim[j][2]) + (Ure[i][2]*Ure[j][1] - Uim[i][2]*Uim[j][1]);
        q12i[p] = (Ure[i][1]*Uim[j][2] + Uim[i][1]*Ure[j][2]) + (Ure[i][2]*Uim[j][1] + Uim[i][2]*Ure[j][1]);
    }

    // ---- 10 canonical triples: {a, PR2[q]} ----
    // c0..c7: a=0, q=0..7 ; c8: a=1, q=4 (rows 2,3) ; c9: a=1, q=5 (rows 2,4)
    const int TA2[10] = {0,0,0,0,0,0,0,0,1,1};
    const int TQ2[10] = {0,1,2,3,4,5,6,7,4,5};
    float sq[10];
    float ssum = 0.f;
    #pragma unroll
    for (int t = 0; t < 10; ++t) {
        int a = TA2[t], p = TQ2[t];
        float pr = (Ure[a][0]*q12r[p] - Uim[a][0]*q12i[p])
                 + (Ure[a][1]*q02r[p] - Uim[a][1]*q02i[p])
                 + (Ure[a][2]*q01r[p] - Uim[a][2]*q01i[p]);
        float pi = (Ure[a][0]*q12i[p] + Uim[a][0]*q12r[p])
                 + (Ure[a][1]*q02i[p] + Uim[a][1]*q02r[p])
                 + (Ure[a][2]*q01i[p] + Uim[a][2]*q01r[p]);
        sq[t] = pr * pr + pi * pi;
        ssum += sq[t];
    }

    // ---- Norm across the 2-lane element pair ----
    ssum += __shfl_xor(ssum, 1, 64);
    float inv = rsqrtf(fmaxf(ssum, 1e-24f));

    if (e < B) {
        float o[10];
        #pragma unroll
        for (int t = 0; t < 10; ++t) o[t] = sqrtf(sq[t]) * inv;
        float* base = out + (size_t)e * 20;
        if (sub == 0) {
            // c0..c7 -> t0..t7 ; c8 -> t10 ; c9 -> t11
            *reinterpret_cast<float4*>(base + 0)  = make_float4(o[0], o[1], o[2], o[3]);
            *reinterpret_cast<float4*>(base + 4)  = make_float4(o[4], o[5], o[6], o[7]);
            *reinterpret_cast<float2*>(base + 10) = make_float2(o[8], o[9]);
        } else {
            // reversed-row triples: c6->t8, c3->t9, c7->t12, c9->t13, c5->t14,
            // c2->t15, c8->t16, c4->t17, c1->t18, c0->t19
            *reinterpret_cast<float2*>(base + 8)  = make_float2(o[6], o[3]);
            *reinterpret_cast<float4*>(base + 12) = make_float4(o[7], o[9], o[5], o[2]);
            *reinterpret_cast<float4*>(base + 16) = make_float4(o[8], o[4], o[1], o[0]);
        }
    }
}

extern "C" void kernel_launch(void* const* d_in, const int* in_sizes, int n_in,
                              void* d_out, int out_size, void* d_ws, size_t ws_size,
                              hipStream_t stream) {
    const float* x            = (const float*)d_in[0];
    const float* params       = (const float*)d_in[1];
    const float* output_phase = (const float*)d_in[2];
    const float* param_phi    = (const float*)d_in[3];
    const float* param_theta  = (const float*)d_in[4];
    const float* input_k      = (const float*)d_in[5];
    const float* input_b      = (const float*)d_in[6];
    int B = in_sizes[0] / 12;

    long long threads = (long long)B * 2;
    int block = 64;
    int grid = (int)((threads + block - 1) / block);
    bqnn_kernel<<<grid, block, 0, stream>>>(x, params, output_phase, param_phi,
                                            param_theta, input_k, input_b,
                                            (float*)d_out, B);
}